// Round 12
// baseline (113.902 us; speedup 1.0000x reference)
//
#include <hip/hip_runtime.h>

#define D_MODEL 1024
#define SEQ     2048
#define BATCH   2
#define NH      16

using u16 = unsigned short;
typedef __bf16 bf16x8 __attribute__((ext_vector_type(8)));
typedef float  f32x4  __attribute__((ext_vector_type(4)));

__device__ __forceinline__ u16 f2bf(float f){
  union { __bf16 h; u16 u; } v; v.h = (__bf16)f; return v.u;
}

__device__ __forceinline__ void gload_lds16(const void* g, void* l){
  __builtin_amdgcn_global_load_lds(
      (const __attribute__((address_space(1))) void*)g,
      (__attribute__((address_space(3))) void*)l, 16, 0, 0);
}

// ---------- kernel 1+2 merged: X fp32->bf16  AND  weights ->bf16 [N][K] ----
__global__ __launch_bounds__(256) void k_prep(
    const float* __restrict__ X, u16* __restrict__ Xb,
    const float* __restrict__ wq, const float* __restrict__ wk,
    const float* __restrict__ wv, const float* __restrict__ w0,
    u16* __restrict__ oq, u16* __restrict__ ok,
    u16* __restrict__ ov, u16* __restrict__ o0)
{
  const int t = threadIdx.x;
  if (blockIdx.x < 4096){
    int i = blockIdx.x*256 + t;
    float4 v = ((const float4*)X)[i];
    ushort4 o; o.x=f2bf(v.x); o.y=f2bf(v.y); o.z=f2bf(v.z); o.w=f2bf(v.w);
    ((ushort4*)Xb)[i] = o;
    return;
  }
  const int bid = blockIdx.x - 4096;
  const int z = bid >> 8, rem = bid & 255;
  const int nt = (rem & 15)*64, kt = (rem >> 4)*64;
  const float* W; u16* O;
  if      (z==0){W=wq;O=oq;}
  else if (z==1){W=wk;O=ok;}
  else if (z==2){W=wv;O=ov;}
  else          {W=w0;O=o0;}
  __shared__ float T[64][65];
  int r0 = t>>4, cb = (t&15)*4;
  #pragma unroll
  for (int j=0;j<4;++j){
    int r = r0 + j*16;
    float4 v = *(const float4*)(W + (size_t)(kt + r)*1024 + nt + cb);
    T[r][cb] = v.x; T[r][cb+1] = v.y; T[r][cb+2] = v.z; T[r][cb+3] = v.w;
  }
  __syncthreads();
  #pragma unroll
  for (int j=0;j<4;++j){
    int rn = r0 + j*16;
    ushort4 o;
    o.x = f2bf(T[cb  ][rn]); o.y = f2bf(T[cb+1][rn]);
    o.z = f2bf(T[cb+2][rn]); o.w = f2bf(T[cb+3][rn]);
    *(ushort4*)(O + (size_t)(nt + rn)*1024 + kt + cb) = o;
  }
}

// ---------- GEMM: 128x128 tile, BK=32, 4-deep counted-vmcnt pipeline -------
// T3/T4: stage K-tile u+3 while computing u (4 LDS buffers); each wave waits
// vmcnt(8) once per tile -> retires exactly tile u+1, leaving u+2/u+3 loads
// in flight ACROSS barriers. 2 phases/tile (16 MFMA each half of ni-range),
// raw s_barrier + setprio. LDS 64KB -> 2 blocks/CU.
// MODE 0: bf16 out, scaleQ applied when bn<1024 (Q columns). MODE 1: f32 out.
template<int MODE>
__global__ __launch_bounds__(256, 2) void k_gemm_p(
    const u16* __restrict__ A, const u16* __restrict__ Bt,
    u16* __restrict__ Ob, float* __restrict__ OF, float scaleQ, int N)
{
  const int K = 1024;
  const int nwg = gridDim.x * gridDim.y;
  const int f = blockIdx.y * gridDim.x + blockIdx.x;
  const int sw = (f & 7) * (nwg >> 3) + (f >> 3);
  const int bxs = sw % gridDim.x, bys = sw / gridDim.x;
  const int bm = bys*128, bn = bxs*128;
  const float scl = (MODE == 0 && bn < 1024) ? scaleQ : 1.0f;
  const int lane = threadIdx.x & 63, w = threadIdx.x >> 6;
  const int hi = lane >> 4, c = lane & 15;
  const int wr = w >> 1, wc = w & 1;
  const int t = threadIdx.x;

  __shared__ u16 As[4][128*32];   // 4 K-tile buffers, 8KB each
  __shared__ u16 Bs[4][128*32];

  // staging: thread t instr i covers row t/4 + i*64, col-u16 (t&3)*8.
  // LDS dest is wave-uniform (base + w*1024 [+4096 for instr 1]); lane*16 implicit.
  const int sr = t >> 2, scol = (t & 3)*8;
  const u16* aS0 = A  + (size_t)(bm + sr)*K + scol;
  const u16* aS1 = A  + (size_t)(bm + 64 + sr)*K + scol;
  const u16* bS0 = Bt + (size_t)(bn + sr)*K + scol;
  const u16* bS1 = Bt + (size_t)(bn + 64 + sr)*K + scol;

  auto stageA = [&](int v){
    char* dst = (char*)&As[v & 3][0] + w*1024;
    gload_lds16(aS0 + v*32, dst);
    gload_lds16(aS1 + v*32, dst + 4096);
  };
  auto stageB = [&](int v){
    char* dst = (char*)&Bs[v & 3][0] + w*1024;
    gload_lds16(bS0 + v*32, dst);
    gload_lds16(bS1 + v*32, dst + 4096);
  };

  f32x4 acc[4][4];
  #pragma unroll
  for (int mi=0;mi<4;++mi)
    #pragma unroll
    for (int ni=0;ni<4;++ni) acc[mi][ni] = (f32x4){0.f,0.f,0.f,0.f};

  // prologue: stage tiles 0,1,2 (12 loads/thread); retire tile 0 (vmcnt 8)
  stageA(0); stageB(0); stageA(1); stageB(1); stageA(2); stageB(2);
  asm volatile("s_waitcnt vmcnt(8)" ::: "memory");
  __builtin_amdgcn_sched_barrier(0);
  __builtin_amdgcn_s_barrier();

  #pragma unroll 1
  for (int u = 0; u < 32; ++u){
    const u16* as = &As[0][0] + (u & 3)*4096;
    const u16* bs = &Bs[0][0] + (u & 3)*4096;
    // ---- phase 0: A-frags + B-frags 0,1 ; stage A(u+3) ; 8 MFMA ----
    bf16x8 af[4];
    #pragma unroll
    for (int mi=0;mi<4;++mi)
      af[mi] = *(const bf16x8*)(as + (wr*64 + mi*16 + c)*32 + hi*8);
    bf16x8 bf0 = *(const bf16x8*)(bs + (wc*64 +  0 + c)*32 + hi*8);
    bf16x8 bf1 = *(const bf16x8*)(bs + (wc*64 + 16 + c)*32 + hi*8);
    if (u < 29) stageA(u+3);
    __builtin_amdgcn_s_barrier();
    __builtin_amdgcn_s_setprio(1);
    #pragma unroll
    for (int mi=0;mi<4;++mi){
      acc[mi][0] = __builtin_amdgcn_mfma_f32_16x16x32_bf16(af[mi], bf0, acc[mi][0], 0,0,0);
      acc[mi][1] = __builtin_amdgcn_mfma_f32_16x16x32_bf16(af[mi], bf1, acc[mi][1], 0,0,0);
    }
    __builtin_amdgcn_s_setprio(0);
    __builtin_amdgcn_s_barrier();
    // ---- phase 1: B-frags 2,3 ; stage B(u+3) ; counted vmcnt ; 8 MFMA ----
    bf16x8 bf2 = *(const bf16x8*)(bs + (wc*64 + 32 + c)*32 + hi*8);
    bf16x8 bf3 = *(const bf16x8*)(bs + (wc*64 + 48 + c)*32 + hi*8);
    if (u < 29) stageB(u+3);
    if (u < 29){
      asm volatile("s_waitcnt vmcnt(8)" ::: "memory");   // retire tile u+1
    } else if (u < 31){
      asm volatile("s_waitcnt vmcnt(0)" ::: "memory");   // tail drain
    }
    __builtin_amdgcn_sched_barrier(0);
    __builtin_amdgcn_s_barrier();
    __builtin_amdgcn_s_setprio(1);
    #pragma unroll
    for (int mi=0;mi<4;++mi){
      acc[mi][2] = __builtin_amdgcn_mfma_f32_16x16x32_bf16(af[mi], bf2, acc[mi][2], 0,0,0);
      acc[mi][3] = __builtin_amdgcn_mfma_f32_16x16x32_bf16(af[mi], bf3, acc[mi][3], 0,0,0);
    }
    __builtin_amdgcn_s_setprio(0);
    __builtin_amdgcn_s_barrier();
  }

  #pragma unroll
  for (int mi=0;mi<4;++mi){
    #pragma unroll
    for (int ni=0;ni<4;++ni){
      int row = bm + wr*64 + mi*16 + hi*4;
      int col = bn + wc*64 + ni*16 + c;
      #pragma unroll
      for (int r=0;r<4;++r){
        if (MODE == 0) Ob[(size_t)(row + r)*N + col] = f2bf(acc[mi][ni][r] * scl);
        else           OF[(size_t)(row + r)*N + col] = acc[mi][ni][r];
      }
    }
  }
}

// ---------- kernel 4: V (QKV col 2048+) -> Vt [B*H][64][S-permuted] --------
__global__ __launch_bounds__(256) void k_trans_v(const u16* __restrict__ QKV,
                                                 u16* __restrict__ Vt){
  int st = blockIdx.x, bh = blockIdx.y;
  int b = bh >> 4, h = bh & 15;
  __shared__ u16 T[64][80];
  int t = threadIdx.x;
  {
    int s = t >> 2, dc = (t & 3)*16;
    const u16* src = QKV + (size_t)(b*SEQ + st*64 + s)*3072 + 2048 + h*64 + dc;
    *(uint4*)&T[s][dc]   = *(const uint4*)(src);
    *(uint4*)&T[s][dc+8] = *(const uint4*)(src + 8);
  }
  __syncthreads();
  {
    int d = t >> 2, sc = (t & 3)*16;
    u16* dst = Vt + ((size_t)bh*64 + d)*SEQ + st*64 + sc;
    u16 vals[16];
    #pragma unroll
    for (int x=0;x<16;++x){
      int p = sc + x;
      int s = (p & 0x23) | ((p & 0x04) << 2) | ((p & 0x18) >> 1);
      vals[x] = T[s][d];
    }
    uint4 w0, w1;
    w0.x = (unsigned)vals[ 0] | ((unsigned)vals[ 1] << 16);
    w0.y = (unsigned)vals[ 2] | ((unsigned)vals[ 3] << 16);
    w0.z = (unsigned)vals[ 4] | ((unsigned)vals[ 5] << 16);
    w0.w = (unsigned)vals[ 6] | ((unsigned)vals[ 7] << 16);
    w1.x = (unsigned)vals[ 8] | ((unsigned)vals[ 9] << 16);
    w1.y = (unsigned)vals[10] | ((unsigned)vals[11] << 16);
    w1.z = (unsigned)vals[12] | ((unsigned)vals[13] << 16);
    w1.w = (unsigned)vals[14] | ((unsigned)vals[15] << 16);
    *(uint4*)(dst)     = w0;
    *(uint4*)(dst + 8) = w1;
  }
}

// ---------- kernel 5: attention (unchanged from R11) ----------
__global__ __launch_bounds__(256, 2) void k_attn(const u16* __restrict__ QKV,
                                                 const u16* __restrict__ Vt,
                                                 u16* __restrict__ AO)
{
  const int bh = blockIdx.x, qt = blockIdx.y;
  const int b = bh >> 4, h = bh & 15;
  const int lane = threadIdx.x & 63, w = threadIdx.x >> 6;  // w = 0..3
  const int qg = w >> 1, kh = w & 1;
  const int hi = lane >> 4, c = lane & 15;

  __shared__ u16 Ks[2][64*64];
  __shared__ u16 Vs[2][64*64];

  const size_t qrow0 = (size_t)(b*SEQ + qt*128 + qg*64 + c);
  bf16x8 qf0[4], qf1[4];
  #pragma unroll
  for (int s=0;s<4;++s){
    qf0[s] = *(const bf16x8*)(QKV + (qrow0 + s*16)*3072 + h*64 + hi*8);
    qf1[s] = *(const bf16x8*)(QKV + (qrow0 + s*16)*3072 + h*64 + 32 + hi*8);
  }

  bf16x8 ones8;
  #pragma unroll
  for (int j=0;j<8;++j) ones8[j] = (__bf16)1.0f;

  f32x4 acc_o[4][4];
  f32x4 acc_l[4];
  #pragma unroll
  for (int s=0;s<4;++s){
    acc_l[s] = (f32x4){0.f,0.f,0.f,0.f};
    #pragma unroll
    for (int n=0;n<4;++n) acc_o[s][n] = (f32x4){0.f,0.f,0.f,0.f};
  }

  const int r0 = w*8 + (lane>>3);
  const int r1 = 32 + r0;
  const int sb = ((((lane&7)*16) ^ ((lane>>3)<<4)) >> 1);
  const u16* kS0 = QKV + (size_t)(b*SEQ + r0)*3072 + 1024 + h*64 + sb;
  const u16* kS1 = QKV + (size_t)(b*SEQ + r1)*3072 + 1024 + h*64 + sb;
  const u16* vS0 = Vt + ((size_t)bh*64 + r0)*SEQ + sb;
  const u16* vS1 = Vt + ((size_t)bh*64 + r1)*SEQ + sb;

  auto stage = [&](int buf){
    gload_lds16(kS0, Ks[buf] + w*512);
    gload_lds16(kS1, Ks[buf] + 2048 + w*512);
    gload_lds16(vS0, Vs[buf] + w*512);
    gload_lds16(vS1, Vs[buf] + 2048 + w*512);
    kS0 += (size_t)64*3072; kS1 += (size_t)64*3072; vS0 += 64; vS1 += 64;
  };

  const int swz = ((c&7)<<4);
  const char* kr0 = (const char*)&Ks[0][0] + (kh*32 + c)*128 + (( 0 + hi*16) ^ swz);
  const char* kr1 = (const char*)&Ks[0][0] + (kh*32 + c)*128 + ((64 + hi*16) ^ swz);
  const char* vr  = (const char*)&Vs[0][0] + c*128 + ((kh*64 + hi*16) ^ swz);

  auto body = [&](int buf){
    const int bo = buf*8192;
    bf16x8 k00 = *(const bf16x8*)(kr0 + bo);
    bf16x8 k01 = *(const bf16x8*)(kr1 + bo);
    bf16x8 k10 = *(const bf16x8*)(kr0 + bo + 2048);
    bf16x8 k11 = *(const bf16x8*)(kr1 + bo + 2048);
    bf16x8 vv0 = *(const bf16x8*)(vr + bo);
    bf16x8 vv1 = *(const bf16x8*)(vr + bo + 2048);
    bf16x8 vv2 = *(const bf16x8*)(vr + bo + 4096);
    bf16x8 vv3 = *(const bf16x8*)(vr + bo + 6144);
    #pragma unroll
    for (int s=0;s<4;++s){
      f32x4 s0 = (f32x4){0.f,0.f,0.f,0.f};
      f32x4 s1 = (f32x4){0.f,0.f,0.f,0.f};
      __builtin_amdgcn_s_setprio(1);
      s0 = __builtin_amdgcn_mfma_f32_16x16x32_bf16(k00, qf0[s], s0, 0,0,0);
      s1 = __builtin_amdgcn_mfma_f32_16x16x32_bf16(k10, qf0[s], s1, 0,0,0);
      s0 = __builtin_amdgcn_mfma_f32_16x16x32_bf16(k01, qf1[s], s0, 0,0,0);
      s1 = __builtin_amdgcn_mfma_f32_16x16x32_bf16(k11, qf1[s], s1, 0,0,0);
      __builtin_amdgcn_s_setprio(0);
      bf16x8 a;
      #pragma unroll
      for (int i=0;i<4;++i){
        a[i]   = (__bf16)__builtin_amdgcn_exp2f(s0[i]);
        a[i+4] = (__bf16)__builtin_amdgcn_exp2f(s1[i]);
      }
      __builtin_amdgcn_s_setprio(1);
      acc_l[s]    = __builtin_amdgcn_mfma_f32_16x16x32_bf16(a, ones8, acc_l[s], 0,0,0);
      acc_o[s][0] = __builtin_amdgcn_mfma_f32_16x16x32_bf16(a, vv0, acc_o[s][0], 0,0,0);
      acc_o[s][1] = __builtin_amdgcn_mfma_f32_16x16x32_bf16(a, vv1, acc_o[s][1], 0,0,0);
      acc_o[s][2] = __builtin_amdgcn_mfma_f32_16x16x32_bf16(a, vv2, acc_o[s][2], 0,0,0);
      acc_o[s][3] = __builtin_amdgcn_mfma_f32_16x16x32_bf16(a, vv3, acc_o[s][3], 0,0,0);
      __builtin_amdgcn_s_setprio(0);
    }
  };

  stage(0);
  __syncthreads();
  #pragma unroll 1
  for (int u = 0; u < SEQ/128; ++u){
    stage(1);
    body(0);
    __syncthreads();
    if (u != SEQ/128 - 1) stage(0);
    body(1);
    __syncthreads();
  }

  float* Of = (float*)&Ks[0][0];
  float* Lf = (float*)&Vs[0][0];
  #pragma unroll
  for (int s=0;s<4;++s){
    if (kh == 1){
      #pragma unroll
      for (int n=0;n<4;++n)
        #pragma unroll
        for (int i=0;i<4;++i)
          Of[qg*1024 + (hi*4+i)*64 + n*16 + c] = acc_o[s][n][i];
      if (c == 0){
        #pragma unroll
        for (int i=0;i<4;++i) Lf[qg*16 + hi*4 + i] = acc_l[s][i];
      }
    }
    __syncthreads();
    if (kh == 0){
      float inv[4];
      #pragma unroll
      for (int i=0;i<4;++i)
        inv[i] = 1.0f / (acc_l[s][i] + Lf[qg*16 + hi*4 + i]);
      size_t obase = (size_t)(b*SEQ + qt*128 + qg*64 + s*16 + hi*4)*D_MODEL + h*64;
      #pragma unroll
      for (int i=0;i<4;++i){
        #pragma unroll
        for (int n=0;n<4;++n){
          float o = acc_o[s][n][i] + Of[qg*1024 + (hi*4+i)*64 + n*16 + c];
          AO[obase + (size_t)i*D_MODEL + n*16 + c] = f2bf(o * inv[i]);
        }
      }
    }
    __syncthreads();
  }
}

extern "C" void kernel_launch(void* const* d_in, const int* in_sizes, int n_in,
                              void* d_out, int out_size, void* d_ws, size_t ws_size,
                              hipStream_t stream)
{
  const float* X  = (const float*)d_in[0];
  const float* Wq = (const float*)d_in[1];
  const float* Wk = (const float*)d_in[2];
  const float* Wv = (const float*)d_in[3];
  const float* W0 = (const float*)d_in[4];
  float* out = (float*)d_out;

  char* ws = (char*)d_ws;
  const size_t MB = 1024*1024;
  u16* Xb    = (u16*)(ws);           // 8 MB  [4096][1024]; reused as AO later
  u16* WqkvT = (u16*)(ws +  8*MB);   // 6 MB  [3072][1024] (Wq,Wk,Wv rows)
  u16* W0T   = (u16*)(ws + 14*MB);   // 2 MB
  u16* QKVb  = (u16*)(ws + 16*MB);   // 24 MB [4096][3072]
  u16* Vt    = (u16*)(ws + 40*MB);   // 8 MB  [B*H][64][SEQ] (keys permuted)
  u16* AO    = Xb;                   // Xb dead after QKV GEMM

  const float scaleQ = 1.4426950408889634f / sqrtf((float)SEQ);
  const int M = BATCH*SEQ;

  k_prep<<<dim3(4096 + 1024), 256, 0, stream>>>(
      X, Xb, Wq, Wk, Wv, W0,
      WqkvT, WqkvT + 1024*1024, WqkvT + 2*1024*1024, W0T);
  k_gemm_p<0><<<dim3(3072/128, M/128), 256, 0, stream>>>(
      Xb, WqkvT, QKVb, nullptr, scaleQ, 3072);
  k_trans_v<<<dim3(SEQ/64, BATCH*NH), 256, 0, stream>>>(QKVb, Vt);
  k_attn<<<dim3(BATCH*NH, SEQ/128), 256, 0, stream>>>(QKVb, Vt, AO);
  k_gemm_p<1><<<dim3(1024/128, M/128), 256, 0, stream>>>(
      AO, W0T, nullptr, out, 1.0f, 1024);
}

// Round 13
// 104.767 us; speedup vs baseline: 1.0872x; 1.0872x over previous
//
#include <hip/hip_runtime.h>

#define D_MODEL 1024
#define SEQ     2048
#define BATCH   2
#define NH      16

using u16 = unsigned short;
typedef __bf16 bf16x8 __attribute__((ext_vector_type(8)));
typedef float  f32x4  __attribute__((ext_vector_type(4)));

__device__ __forceinline__ u16 f2bf(float f){
  union { __bf16 h; u16 u; } v; v.h = (__bf16)f; return v.u;
}

__device__ __forceinline__ void gload_lds16(const void* g, void* l){
  __builtin_amdgcn_global_load_lds(
      (const __attribute__((address_space(1))) void*)g,
      (__attribute__((address_space(3))) void*)l, 16, 0, 0);
}

// ---------- kernel 1+2 merged: X fp32->bf16  AND  weights ->bf16 [N][K] ----
__global__ __launch_bounds__(256) void k_prep(
    const float* __restrict__ X, u16* __restrict__ Xb,
    const float* __restrict__ wq, const float* __restrict__ wk,
    const float* __restrict__ wv, const float* __restrict__ w0,
    u16* __restrict__ oq, u16* __restrict__ ok,
    u16* __restrict__ ov, u16* __restrict__ o0)
{
  const int t = threadIdx.x;
  if (blockIdx.x < 4096){
    int i = blockIdx.x*256 + t;
    float4 v = ((const float4*)X)[i];
    ushort4 o; o.x=f2bf(v.x); o.y=f2bf(v.y); o.z=f2bf(v.z); o.w=f2bf(v.w);
    ((ushort4*)Xb)[i] = o;
    return;
  }
  const int bid = blockIdx.x - 4096;
  const int z = bid >> 8, rem = bid & 255;
  const int nt = (rem & 15)*64, kt = (rem >> 4)*64;
  const float* W; u16* O;
  if      (z==0){W=wq;O=oq;}
  else if (z==1){W=wk;O=ok;}
  else if (z==2){W=wv;O=ov;}
  else          {W=w0;O=o0;}
  __shared__ float T[64][65];
  int r0 = t>>4, cb = (t&15)*4;
  #pragma unroll
  for (int j=0;j<4;++j){
    int r = r0 + j*16;
    float4 v = *(const float4*)(W + (size_t)(kt + r)*1024 + nt + cb);
    T[r][cb] = v.x; T[r][cb+1] = v.y; T[r][cb+2] = v.z; T[r][cb+3] = v.w;
  }
  __syncthreads();
  #pragma unroll
  for (int j=0;j<4;++j){
    int rn = r0 + j*16;
    ushort4 o;
    o.x = f2bf(T[cb  ][rn]); o.y = f2bf(T[cb+1][rn]);
    o.z = f2bf(T[cb+2][rn]); o.w = f2bf(T[cb+3][rn]);
    *(ushort4*)(O + (size_t)(nt + rn)*1024 + kt + cb) = o;
  }
}

// ---------- kernel 3: fused QKV GEMM (R11 2-phase structure, reverted) -----
// R12 lesson: 4-deep counted-vmcnt pipeline on this 128x128/4-wave structure
// REGRESSED (45 vs 38 us) -- keep the simple 2-phase dbuf.
// NEW: V columns (bn>=2048) write DIRECTLY to Vt transposed+key-permuted
// (fuses k_trans_v away). p(s) = (s&0x23)|((s&0x10)>>2)|((s&0x0C)<<1) is the
// inverse of trans_v's verified s(p); low 2 bits pass through, so the 4
// per-thread rows land at 4 consecutive Vt u16 -> one ushort4 store.
__global__ __launch_bounds__(256) void k_gemm_qkv(
    const u16* __restrict__ A, const u16* __restrict__ Bt,
    u16* __restrict__ Ob, u16* __restrict__ Vt, float scaleQ)
{
  const int K = 1024, N = 3072;
  const int nwg = gridDim.x * gridDim.y;
  const int f = blockIdx.y * gridDim.x + blockIdx.x;
  const int sw = (f & 7) * (nwg >> 3) + (f >> 3);
  const int bxs = sw % gridDim.x, bys = sw / gridDim.x;
  const int bm = bys*128, bn = bxs*128;
  const float scl = (bn < 1024) ? scaleQ : 1.0f;
  const int lane = threadIdx.x & 63, w = threadIdx.x >> 6;
  const int hi = lane >> 4, c = lane & 15;
  const int wr = w >> 1, wc = w & 1;

  __shared__ u16 As[2][128*32];
  __shared__ u16 Bs[2][128*32];

  const int i0 = 2*w, i1 = 2*w+1;
  const int rA0 = i0*16 + (lane>>2), rA1 = i1*16 + (lane>>2);
  const int cA  = (lane&3)*8;
  const u16* aS0 = A  + (size_t)(bm + rA0)*K + cA;
  const u16* aS1 = A  + (size_t)(bm + rA1)*K + cA;
  const u16* bS0 = Bt + (size_t)(bn + rA0)*K + cA;
  const u16* bS1 = Bt + (size_t)(bn + rA1)*K + cA;

  auto stage = [&](int buf, int kk){
    gload_lds16(aS0 + kk, As[buf] + i0*512);
    gload_lds16(aS1 + kk, As[buf] + i1*512);
    gload_lds16(bS0 + kk, Bs[buf] + i0*512);
    gload_lds16(bS1 + kk, Bs[buf] + i1*512);
  };

  f32x4 acc[4][4];
  #pragma unroll
  for (int mi=0;mi<4;++mi)
    #pragma unroll
    for (int ni=0;ni<4;++ni) acc[mi][ni] = (f32x4){0.f,0.f,0.f,0.f};

  stage(0, 0);
  __syncthreads();
  int cur = 0;
  for (int kk = 0; kk < K; kk += 32){
    if (kk + 32 < K) stage(cur^1, kk + 32);
    const u16* as = As[cur];
    const u16* bs = Bs[cur];
    bf16x8 af[4], bfr[4];
    #pragma unroll
    for (int mi=0;mi<4;++mi)
      af[mi] = *(const bf16x8*)(as + (wr*64 + mi*16 + c)*32 + hi*8);
    #pragma unroll
    for (int ni=0;ni<4;++ni)
      bfr[ni] = *(const bf16x8*)(bs + (wc*64 + ni*16 + c)*32 + hi*8);
    #pragma unroll
    for (int mi=0;mi<4;++mi)
      #pragma unroll
      for (int ni=0;ni<4;++ni)
        acc[mi][ni] = __builtin_amdgcn_mfma_f32_16x16x32_bf16(af[mi], bfr[ni], acc[mi][ni], 0, 0, 0);
    __syncthreads();
    cur ^= 1;
  }

  if (bn < 2048){
    // Q/K columns: normal row-major bf16 write
    #pragma unroll
    for (int mi=0;mi<4;++mi){
      #pragma unroll
      for (int ni=0;ni<4;++ni){
        int row = bm + wr*64 + mi*16 + hi*4;
        int col = bn + wc*64 + ni*16 + c;
        #pragma unroll
        for (int r=0;r<4;++r)
          Ob[(size_t)(row + r)*N + col] = f2bf(acc[mi][ni][r] * scl);
      }
    }
  } else {
    // V columns: fused transpose + key-permute into Vt [B*H][64][S-perm]
    #pragma unroll
    for (int mi=0;mi<4;++mi){
      int row = bm + wr*64 + mi*16 + hi*4;           // token s (4-aligned)
      int b_  = row >> 11, s_ = row & 2047;
      int st  = s_ >> 6,  sl = s_ & 63;
      int p   = (sl & 0x23) | ((sl & 0x10) >> 2) | ((sl & 0x0C) << 1);
      #pragma unroll
      for (int ni=0;ni<4;++ni){
        int col = (bn - 2048) + wc*64 + ni*16 + c;    // d_full in [0,1024)
        int h_ = col >> 6, d_ = col & 63;
        u16* dst = Vt + ((size_t)(b_*16 + h_)*64 + d_)*SEQ + st*64 + p;
        ushort4 o;
        o.x = f2bf(acc[mi][ni][0]); o.y = f2bf(acc[mi][ni][1]);
        o.z = f2bf(acc[mi][ni][2]); o.w = f2bf(acc[mi][ni][3]);
        *(ushort4*)dst = o;
      }
    }
  }
}

// ---------- kernel 6: out-proj GEMM (R11 2-phase, reverted) ----------------
__global__ __launch_bounds__(256) void k_gemm_out(
    const u16* __restrict__ A, const u16* __restrict__ Bt,
    float* __restrict__ OF)
{
  const int K = 1024, N = 1024;
  const int nwg = gridDim.x * gridDim.y;
  const int f = blockIdx.y * gridDim.x + blockIdx.x;
  const int sw = (f & 7) * (nwg >> 3) + (f >> 3);
  const int bxs = sw % gridDim.x, bys = sw / gridDim.x;
  const int bm = bys*128, bn = bxs*128;
  const int lane = threadIdx.x & 63, w = threadIdx.x >> 6;
  const int hi = lane >> 4, c = lane & 15;
  const int wr = w >> 1, wc = w & 1;

  __shared__ u16 As[2][128*32];
  __shared__ u16 Bs[2][128*32];

  const int i0 = 2*w, i1 = 2*w+1;
  const int rA0 = i0*16 + (lane>>2), rA1 = i1*16 + (lane>>2);
  const int cA  = (lane&3)*8;
  const u16* aS0 = A  + (size_t)(bm + rA0)*K + cA;
  const u16* aS1 = A  + (size_t)(bm + rA1)*K + cA;
  const u16* bS0 = Bt + (size_t)(bn + rA0)*K + cA;
  const u16* bS1 = Bt + (size_t)(bn + rA1)*K + cA;

  auto stage = [&](int buf, int kk){
    gload_lds16(aS0 + kk, As[buf] + i0*512);
    gload_lds16(aS1 + kk, As[buf] + i1*512);
    gload_lds16(bS0 + kk, Bs[buf] + i0*512);
    gload_lds16(bS1 + kk, Bs[buf] + i1*512);
  };

  f32x4 acc[4][4];
  #pragma unroll
  for (int mi=0;mi<4;++mi)
    #pragma unroll
    for (int ni=0;ni<4;++ni) acc[mi][ni] = (f32x4){0.f,0.f,0.f,0.f};

  stage(0, 0);
  __syncthreads();
  int cur = 0;
  for (int kk = 0; kk < K; kk += 32){
    if (kk + 32 < K) stage(cur^1, kk + 32);
    const u16* as = As[cur];
    const u16* bs = Bs[cur];
    bf16x8 af[4], bfr[4];
    #pragma unroll
    for (int mi=0;mi<4;++mi)
      af[mi] = *(const bf16x8*)(as + (wr*64 + mi*16 + c)*32 + hi*8);
    #pragma unroll
    for (int ni=0;ni<4;++ni)
      bfr[ni] = *(const bf16x8*)(bs + (wc*64 + ni*16 + c)*32 + hi*8);
    #pragma unroll
    for (int mi=0;mi<4;++mi)
      #pragma unroll
      for (int ni=0;ni<4;++ni)
        acc[mi][ni] = __builtin_amdgcn_mfma_f32_16x16x32_bf16(af[mi], bfr[ni], acc[mi][ni], 0, 0, 0);
    __syncthreads();
    cur ^= 1;
  }
  #pragma unroll
  for (int mi=0;mi<4;++mi){
    #pragma unroll
    for (int ni=0;ni<4;++ni){
      int row = bm + wr*64 + mi*16 + hi*4;
      int col = bn + wc*64 + ni*16 + c;
      #pragma unroll
      for (int r=0;r<4;++r)
        OF[(size_t)(row + r)*N + col] = acc[mi][ni][r];
    }
  }
}

// ---------- kernel 5: attention (unchanged from R11) ----------
__global__ __launch_bounds__(256, 2) void k_attn(const u16* __restrict__ QKV,
                                                 const u16* __restrict__ Vt,
                                                 u16* __restrict__ AO)
{
  const int bh = blockIdx.x, qt = blockIdx.y;
  const int b = bh >> 4, h = bh & 15;
  const int lane = threadIdx.x & 63, w = threadIdx.x >> 6;  // w = 0..3
  const int qg = w >> 1, kh = w & 1;
  const int hi = lane >> 4, c = lane & 15;

  __shared__ u16 Ks[2][64*64];
  __shared__ u16 Vs[2][64*64];

  const size_t qrow0 = (size_t)(b*SEQ + qt*128 + qg*64 + c);
  bf16x8 qf0[4], qf1[4];
  #pragma unroll
  for (int s=0;s<4;++s){
    qf0[s] = *(const bf16x8*)(QKV + (qrow0 + s*16)*3072 + h*64 + hi*8);
    qf1[s] = *(const bf16x8*)(QKV + (qrow0 + s*16)*3072 + h*64 + 32 + hi*8);
  }

  bf16x8 ones8;
  #pragma unroll
  for (int j=0;j<8;++j) ones8[j] = (__bf16)1.0f;

  f32x4 acc_o[4][4];
  f32x4 acc_l[4];
  #pragma unroll
  for (int s=0;s<4;++s){
    acc_l[s] = (f32x4){0.f,0.f,0.f,0.f};
    #pragma unroll
    for (int n=0;n<4;++n) acc_o[s][n] = (f32x4){0.f,0.f,0.f,0.f};
  }

  const int r0 = w*8 + (lane>>3);
  const int r1 = 32 + r0;
  const int sb = ((((lane&7)*16) ^ ((lane>>3)<<4)) >> 1);
  const u16* kS0 = QKV + (size_t)(b*SEQ + r0)*3072 + 1024 + h*64 + sb;
  const u16* kS1 = QKV + (size_t)(b*SEQ + r1)*3072 + 1024 + h*64 + sb;
  const u16* vS0 = Vt + ((size_t)bh*64 + r0)*SEQ + sb;
  const u16* vS1 = Vt + ((size_t)bh*64 + r1)*SEQ + sb;

  auto stage = [&](int buf){
    gload_lds16(kS0, Ks[buf] + w*512);
    gload_lds16(kS1, Ks[buf] + 2048 + w*512);
    gload_lds16(vS0, Vs[buf] + w*512);
    gload_lds16(vS1, Vs[buf] + 2048 + w*512);
    kS0 += (size_t)64*3072; kS1 += (size_t)64*3072; vS0 += 64; vS1 += 64;
  };

  const int swz = ((c&7)<<4);
  const char* kr0 = (const char*)&Ks[0][0] + (kh*32 + c)*128 + (( 0 + hi*16) ^ swz);
  const char* kr1 = (const char*)&Ks[0][0] + (kh*32 + c)*128 + ((64 + hi*16) ^ swz);
  const char* vr  = (const char*)&Vs[0][0] + c*128 + ((kh*64 + hi*16) ^ swz);

  auto body = [&](int buf){
    const int bo = buf*8192;
    bf16x8 k00 = *(const bf16x8*)(kr0 + bo);
    bf16x8 k01 = *(const bf16x8*)(kr1 + bo);
    bf16x8 k10 = *(const bf16x8*)(kr0 + bo + 2048);
    bf16x8 k11 = *(const bf16x8*)(kr1 + bo + 2048);
    bf16x8 vv0 = *(const bf16x8*)(vr + bo);
    bf16x8 vv1 = *(const bf16x8*)(vr + bo + 2048);
    bf16x8 vv2 = *(const bf16x8*)(vr + bo + 4096);
    bf16x8 vv3 = *(const bf16x8*)(vr + bo + 6144);
    #pragma unroll
    for (int s=0;s<4;++s){
      f32x4 s0 = (f32x4){0.f,0.f,0.f,0.f};
      f32x4 s1 = (f32x4){0.f,0.f,0.f,0.f};
      __builtin_amdgcn_s_setprio(1);
      s0 = __builtin_amdgcn_mfma_f32_16x16x32_bf16(k00, qf0[s], s0, 0,0,0);
      s1 = __builtin_amdgcn_mfma_f32_16x16x32_bf16(k10, qf0[s], s1, 0,0,0);
      s0 = __builtin_amdgcn_mfma_f32_16x16x32_bf16(k01, qf1[s], s0, 0,0,0);
      s1 = __builtin_amdgcn_mfma_f32_16x16x32_bf16(k11, qf1[s], s1, 0,0,0);
      __builtin_amdgcn_s_setprio(0);
      bf16x8 a;
      #pragma unroll
      for (int i=0;i<4;++i){
        a[i]   = (__bf16)__builtin_amdgcn_exp2f(s0[i]);
        a[i+4] = (__bf16)__builtin_amdgcn_exp2f(s1[i]);
      }
      __builtin_amdgcn_s_setprio(1);
      acc_l[s]    = __builtin_amdgcn_mfma_f32_16x16x32_bf16(a, ones8, acc_l[s], 0,0,0);
      acc_o[s][0] = __builtin_amdgcn_mfma_f32_16x16x32_bf16(a, vv0, acc_o[s][0], 0,0,0);
      acc_o[s][1] = __builtin_amdgcn_mfma_f32_16x16x32_bf16(a, vv1, acc_o[s][1], 0,0,0);
      acc_o[s][2] = __builtin_amdgcn_mfma_f32_16x16x32_bf16(a, vv2, acc_o[s][2], 0,0,0);
      acc_o[s][3] = __builtin_amdgcn_mfma_f32_16x16x32_bf16(a, vv3, acc_o[s][3], 0,0,0);
      __builtin_amdgcn_s_setprio(0);
    }
  };

  stage(0);
  __syncthreads();
  #pragma unroll 1
  for (int u = 0; u < SEQ/128; ++u){
    stage(1);
    body(0);
    __syncthreads();
    if (u != SEQ/128 - 1) stage(0);
    body(1);
    __syncthreads();
  }

  float* Of = (float*)&Ks[0][0];
  float* Lf = (float*)&Vs[0][0];
  #pragma unroll
  for (int s=0;s<4;++s){
    if (kh == 1){
      #pragma unroll
      for (int n=0;n<4;++n)
        #pragma unroll
        for (int i=0;i<4;++i)
          Of[qg*1024 + (hi*4+i)*64 + n*16 + c] = acc_o[s][n][i];
      if (c == 0){
        #pragma unroll
        for (int i=0;i<4;++i) Lf[qg*16 + hi*4 + i] = acc_l[s][i];
      }
    }
    __syncthreads();
    if (kh == 0){
      float inv[4];
      #pragma unroll
      for (int i=0;i<4;++i)
        inv[i] = 1.0f / (acc_l[s][i] + Lf[qg*16 + hi*4 + i]);
      size_t obase = (size_t)(b*SEQ + qt*128 + qg*64 + s*16 + hi*4)*D_MODEL + h*64;
      #pragma unroll
      for (int i=0;i<4;++i){
        #pragma unroll
        for (int n=0;n<4;++n){
          float o = acc_o[s][n][i] + Of[qg*1024 + (hi*4+i)*64 + n*16 + c];
          AO[obase + (size_t)i*D_MODEL + n*16 + c] = f2bf(o * inv[i]);
        }
      }
    }
    __syncthreads();
  }
}

extern "C" void kernel_launch(void* const* d_in, const int* in_sizes, int n_in,
                              void* d_out, int out_size, void* d_ws, size_t ws_size,
                              hipStream_t stream)
{
  const float* X  = (const float*)d_in[0];
  const float* Wq = (const float*)d_in[1];
  const float* Wk = (const float*)d_in[2];
  const float* Wv = (const float*)d_in[3];
  const float* W0 = (const float*)d_in[4];
  float* out = (float*)d_out;

  char* ws = (char*)d_ws;
  const size_t MB = 1024*1024;
  u16* Xb    = (u16*)(ws);           // 8 MB  [4096][1024]; reused as AO later
  u16* WqkvT = (u16*)(ws +  8*MB);   // 6 MB  [3072][1024] (Wq,Wk,Wv rows)
  u16* W0T   = (u16*)(ws + 14*MB);   // 2 MB
  u16* QKVb  = (u16*)(ws + 16*MB);   // 24 MB [4096][3072] (V third unused)
  u16* Vt    = (u16*)(ws + 40*MB);   // 8 MB  [B*H][64][SEQ] (keys permuted)
  u16* AO    = Xb;                   // Xb dead after QKV GEMM

  const float scaleQ = 1.4426950408889634f / sqrtf((float)SEQ);
  const int M = BATCH*SEQ;

  k_prep<<<dim3(4096 + 1024), 256, 0, stream>>>(
      X, Xb, Wq, Wk, Wv, W0,
      WqkvT, WqkvT + 1024*1024, WqkvT + 2*1024*1024, W0T);
  k_gemm_qkv<<<dim3(3072/128, M/128), 256, 0, stream>>>(
      Xb, WqkvT, QKVb, Vt, scaleQ);
  k_attn<<<dim3(BATCH*NH, SEQ/128), 256, 0, stream>>>(QKVb, Vt, AO);
  k_gemm_out<<<dim3(1024/128, M/128), 256, 0, stream>>>(AO, W0T, out);
}